// Round 1
// baseline (1642.644 us; speedup 1.0000x reference)
//
#include <hip/hip_runtime.h>
#include <hip/hip_bf16.h>
#include <stdint.h>

#define L_SEQ 2048
#define DMODEL 768
#define DI_ 1536
#define E2_ 3072
#define NLAYER 2
#define SSTATE 16
#define DBCN 80
#define KPAD 64
#define VOCAB 32000

typedef __bf16 bf16x8 __attribute__((ext_vector_type(8)));
typedef float f32x4 __attribute__((ext_vector_type(4)));

__device__ __forceinline__ unsigned short f2bf(float x) {
  union { float f; uint32_t u; } v; v.f = x;
  uint32_t r = (v.u + 0x7FFFu + ((v.u >> 16) & 1u)) >> 16;
  return (unsigned short)r;
}
__device__ __forceinline__ float siluf_(float x) { return x / (1.f + __expf(-x)); }
__device__ __forceinline__ float softplusf_(float x) {
  return fmaxf(x, 0.f) + log1pf(__expf(-fabsf(x)));
}

// ---------------- weight conversion ----------------
__global__ __launch_bounds__(256) void cvt2_kernel(const float* __restrict__ f,
                                                   const float* __restrict__ b,
                                                   unsigned short* __restrict__ dst, long n) {
  long i = (long)blockIdx.x * 256 + threadIdx.x;
  if (i >= n) return;
  const float* s = blockIdx.z ? b : f;
  dst[(long)blockIdx.z * n + i] = f2bf(s[i]);
}
__global__ __launch_bounds__(256) void cvt1_kernel(const float* __restrict__ s,
                                                   unsigned short* __restrict__ dst, long n) {
  long i = (long)blockIdx.x * 256 + threadIdx.x;
  if (i >= n) return;
  dst[i] = f2bf(s[i]);
}
// dt_w (NLAYER*DI_ rows x 48) -> padded (x64)
__global__ __launch_bounds__(256) void cvtdtw_kernel(const float* __restrict__ f,
                                                     const float* __restrict__ b,
                                                     unsigned short* __restrict__ dst) {
  long n = (long)NLAYER * DI_ * KPAD;
  long i = (long)blockIdx.x * 256 + threadIdx.x;
  if (i >= n) return;
  long r = i >> 6; int c = (int)(i & 63);
  const float* s = blockIdx.z ? b : f;
  dst[(long)blockIdx.z * n + i] = f2bf(c < 48 ? s[r * 48 + c] : 0.f);
}

// ---------------- embedding gather (+flip for dir=1) ----------------
__global__ __launch_bounds__(256) void gather_kernel(const int* __restrict__ ids,
                                                     const float* __restrict__ emb,
                                                     float* __restrict__ res) {
  int idx = blockIdx.x * 256 + threadIdx.x;           // over L*D
  int z = blockIdx.z;
  int l = idx / DMODEL, c = idx % DMODEL;
  int srcl = z ? (L_SEQ - 1 - l) : l;
  res[(size_t)z * L_SEQ * DMODEL + idx] = emb[(size_t)ids[srcl] * DMODEL + c];
}

// ---------------- residual add + rmsnorm -> bf16 ----------------
__global__ __launch_bounds__(256) void addnorm_kernel(float* __restrict__ res,
                                                      const float* __restrict__ hid,
                                                      const float* __restrict__ wf,
                                                      const float* __restrict__ wb, int woff,
                                                      unsigned short* __restrict__ out) {
  int z = blockIdx.z, l = blockIdx.x, t = threadIdx.x;
  const float* w = (z ? wb : wf) + woff;
  size_t base = ((size_t)z * L_SEQ + l) * DMODEL;
  float v[3]; float ss = 0.f;
  #pragma unroll
  for (int i = 0; i < 3; ++i) {
    int c = t + i * 256;
    float x = res[base + c];
    if (hid) { x += hid[base + c]; res[base + c] = x; }
    v[i] = x; ss += x * x;
  }
  #pragma unroll
  for (int m = 32; m; m >>= 1) ss += __shfl_xor(ss, m);
  __shared__ float red[4];
  if ((t & 63) == 0) red[t >> 6] = ss;
  __syncthreads();
  ss = red[0] + red[1] + red[2] + red[3];
  float inv = rsqrtf(ss * (1.f / DMODEL) + 1e-5f);
  #pragma unroll
  for (int i = 0; i < 3; ++i) {
    int c = t + i * 256;
    out[base + c] = f2bf(v[i] * inv * w[c]);
  }
}

// final rmsnorm(hid+res) -> bf16 into hcat with flip+col-offset for dir=1
__global__ __launch_bounds__(256) void finalcat_kernel(const float* __restrict__ res,
                                                       const float* __restrict__ hid,
                                                       const float* __restrict__ wf,
                                                       const float* __restrict__ wb,
                                                       unsigned short* __restrict__ hcat) {
  int z = blockIdx.z, l = blockIdx.x, t = threadIdx.x;
  const float* w = z ? wb : wf;
  size_t base = ((size_t)z * L_SEQ + l) * DMODEL;
  float v[3]; float ss = 0.f;
  #pragma unroll
  for (int i = 0; i < 3; ++i) {
    int c = t + i * 256;
    float x = res[base + c] + hid[base + c];
    v[i] = x; ss += x * x;
  }
  #pragma unroll
  for (int m = 32; m; m >>= 1) ss += __shfl_xor(ss, m);
  __shared__ float red[4];
  if ((t & 63) == 0) red[t >> 6] = ss;
  __syncthreads();
  ss = red[0] + red[1] + red[2] + red[3];
  float inv = rsqrtf(ss * (1.f / DMODEL) + 1e-5f);
  int outl = z ? (L_SEQ - 1 - l) : l;
  #pragma unroll
  for (int i = 0; i < 3; ++i) {
    int c = t + i * 256;
    hcat[(size_t)outl * DI_ + z * DMODEL + c] = f2bf(v[i] * inv * w[c]);
  }
}

// ---------------- circular depthwise conv K=4 + silu ----------------
__global__ __launch_bounds__(256) void conv_kernel(const float* __restrict__ xz,
                                                   const float* __restrict__ cwf,
                                                   const float* __restrict__ cwb,
                                                   const float* __restrict__ cbf,
                                                   const float* __restrict__ cbb, int layer,
                                                   float* __restrict__ xf,
                                                   unsigned short* __restrict__ xbf) {
  int z = blockIdx.z;
  int idx = blockIdx.x * 256 + threadIdx.x;           // over L*DI
  int l = idx / DI_, d = idx % DI_;
  const float* cw = (z ? cwb : cwf) + layer * DI_ * 4;
  const float* cb = (z ? cbb : cbf) + layer * DI_;
  const float* xzp = xz + (size_t)z * L_SEQ * E2_;
  float acc = cb[d];
  #pragma unroll
  for (int k = 0; k < 4; ++k) {
    int ls = (l + k - 3 + L_SEQ) & (L_SEQ - 1);
    acc += cw[d * 4 + k] * xzp[(size_t)ls * E2_ + d];
  }
  float s = siluf_(acc);
  size_t o = (size_t)z * L_SEQ * DI_ + idx;
  xf[o] = s;
  xbf[o] = f2bf(s);
}

// ---------------- dbc f32 -> bf16, pad 48->64 ----------------
__global__ __launch_bounds__(256) void dbcpad_kernel(const float* __restrict__ dbc,
                                                     unsigned short* __restrict__ out) {
  int z = blockIdx.z;
  int idx = blockIdx.x * 256 + threadIdx.x;           // over L*KPAD
  int l = idx >> 6, c = idx & 63;
  float v = (c < 48) ? dbc[(size_t)z * L_SEQ * DBCN + (size_t)l * DBCN + c] : 0.f;
  out[(size_t)z * L_SEQ * KPAD + idx] = f2bf(v);
}

// ---------------- selective scan ----------------
// block: 256 thr = 16 d-channels x 16 states. grid (DI/16, 1, 2)
__global__ __launch_bounds__(256) void scan_kernel(const float* __restrict__ delta, // [z][L][DI]
                                                   const float* __restrict__ u,     // [z][L][DI]
                                                   const float* __restrict__ dbc,   // [z][L][80]
                                                   const float* __restrict__ Af,
                                                   const float* __restrict__ Ab, int aoff,
                                                   float* __restrict__ ys) {        // [z][L][DI]
  const int z = blockIdx.z;
  const int d0 = blockIdx.x * 16;
  const int tid = threadIdx.x;
  const int s = tid & 15;
  const int g = tid >> 4;
  const int d = d0 + g;
  __shared__ float sd[16 * 65], su2[16 * 65], sb2[16 * 65], sc2[16 * 65], sy2[16 * 65];
  const size_t zo = (size_t)z * L_SEQ * DI_;
  const float* dl = delta + zo;
  const float* ul = u + zo;
  const float* bc = dbc + (size_t)z * L_SEQ * DBCN;
  const float* Alog = (z ? Ab : Af) + aoff;
  const float A = -__expf(Alog[d * SSTATE + s]);
  float h = 0.f;
  for (int l0 = 0; l0 < L_SEQ; l0 += 64) {
    #pragma unroll
    for (int i = 0; i < 4; ++i) {
      int idx = tid + i * 256;
      int di = idx & 15, li = idx >> 4;
      size_t gl = (size_t)(l0 + li);
      sd[di * 65 + li]  = dl[gl * DI_ + d0 + di];
      su2[di * 65 + li] = ul[gl * DI_ + d0 + di];
      sb2[di * 65 + li] = bc[gl * DBCN + 48 + di];
      sc2[di * 65 + li] = bc[gl * DBCN + 64 + di];
    }
    __syncthreads();
    for (int t = 0; t < 64; ++t) {
      float dlt = sd[g * 65 + t];
      float uu  = su2[g * 65 + t];
      float bb  = sb2[s * 65 + t];
      float cc  = sc2[s * 65 + t];
      float a = __expf(dlt * A);
      h = a * h + dlt * uu * bb;
      float p = h * cc;
      p += __shfl_xor(p, 1);
      p += __shfl_xor(p, 2);
      p += __shfl_xor(p, 4);
      p += __shfl_xor(p, 8);
      if (s == 0) sy2[g * 65 + t] = p;
    }
    __syncthreads();
    #pragma unroll
    for (int i = 0; i < 4; ++i) {
      int idx = tid + i * 256;
      int di = idx & 15, li = idx >> 4;
      ys[zo + (size_t)(l0 + li) * DI_ + d0 + di] = sy2[di * 65 + li];
    }
    __syncthreads();
  }
}

// ---------------- y = (ys + Dp*x) * silu(z) -> bf16 ----------------
__global__ __launch_bounds__(256) void ycomb_kernel(const float* __restrict__ ys,
                                                    const float* __restrict__ xf,
                                                    const float* __restrict__ xz,
                                                    const float* __restrict__ Dpf,
                                                    const float* __restrict__ Dpb, int doff,
                                                    unsigned short* __restrict__ yb) {
  int z = blockIdx.z;
  int idx = blockIdx.x * 256 + threadIdx.x;           // over L*DI
  int l = idx / DI_, i = idx % DI_;
  const float* Dp = (z ? Dpb : Dpf) + doff;
  float zz = xz[(size_t)z * L_SEQ * E2_ + (size_t)l * E2_ + DI_ + i];
  size_t o = (size_t)z * L_SEQ * DI_ + idx;
  float v = (ys[o] + Dp[i] * xf[o]) * siluf_(zz);
  yb[o] = f2bf(v);
}

// ---------------- generic bf16 MFMA GEMM: C[M,N] = A[M,K] * B[N,K]^T ----------------
// EPI: 0 = f32 store, 1 = softplus(v + bias[col]) f32 store, 2 = bf16 store
template <int EPI>
__global__ __launch_bounds__(256)
void gemm_bt(const unsigned short* __restrict__ Ag, long sAz,
             const unsigned short* __restrict__ Bg, long sBz,
             float* __restrict__ Cf, unsigned short* __restrict__ Cb, long sCz,
             int M, int N, int K,
             const float* __restrict__ bias, long sBiasz) {
  __shared__ __align__(16) unsigned short sA[128 * 64];
  __shared__ __align__(16) unsigned short sB[128 * 64];
  const int tid = threadIdx.x;
  const int lane = tid & 63;
  const int wv = tid >> 6;
  const int z = blockIdx.z;
  const int m0 = blockIdx.y * 128;
  const int n0 = blockIdx.x * 128;
  const unsigned short* A = Ag + (size_t)z * sAz;
  const unsigned short* B = Bg + (size_t)z * sBz;
  const int wm = (wv >> 1) * 64;
  const int wn = (wv & 1) * 64;
  const int lr = lane & 15;
  const int lk8 = (lane >> 4) * 8;

  f32x4 acc[4][4] = {};

  for (int k0 = 0; k0 < K; k0 += 64) {
    #pragma unroll
    for (int i = 0; i < 4; ++i) {
      int c = tid + i * 256;
      int row = c >> 3;
      int kc = (c & 7) * 8;
      int ra = m0 + row; if (ra > M - 1) ra = M - 1;
      int rb = n0 + row; if (rb > N - 1) rb = N - 1;
      uint4 va = *(const uint4*)(A + (size_t)ra * K + (k0 + kc));
      uint4 vb = *(const uint4*)(B + (size_t)rb * K + (k0 + kc));
      *(uint4*)(sA + row * 64 + kc) = va;
      *(uint4*)(sB + row * 64 + kc) = vb;
    }
    __syncthreads();
    #pragma unroll
    for (int kk = 0; kk < 64; kk += 32) {
      bf16x8 af[4], bfr[4];
      #pragma unroll
      for (int i = 0; i < 4; ++i) {
        af[i]  = *(const bf16x8*)(sA + (wm + i * 16 + lr) * 64 + kk + lk8);
        bfr[i] = *(const bf16x8*)(sB + (wn + i * 16 + lr) * 64 + kk + lk8);
      }
      #pragma unroll
      for (int mi = 0; mi < 4; ++mi)
        #pragma unroll
        for (int ni = 0; ni < 4; ++ni)
          acc[mi][ni] = __builtin_amdgcn_mfma_f32_16x16x32_bf16(af[mi], bfr[ni], acc[mi][ni], 0, 0, 0);
    }
    __syncthreads();
  }

  const int orow0 = m0 + wm + (lane >> 4) * 4;
  const int ocol0 = n0 + wn + lr;
  #pragma unroll
  for (int mi = 0; mi < 4; ++mi) {
    #pragma unroll
    for (int ni = 0; ni < 4; ++ni) {
      int col = ocol0 + ni * 16;
      if (col >= N) continue;
      #pragma unroll
      for (int j = 0; j < 4; ++j) {
        int row = orow0 + mi * 16 + j;
        if (row >= M) continue;
        float v = acc[mi][ni][j];
        if constexpr (EPI == 1) v = softplusf_(v + bias[(size_t)z * sBiasz + col]);
        if constexpr (EPI == 2) {
          Cb[(size_t)z * sCz + (size_t)row * N + col] = f2bf(v);
        } else {
          Cf[(size_t)z * sCz + (size_t)row * N + col] = v;
        }
      }
    }
  }
}

// ==================== host launcher ====================
extern "C" void kernel_launch(void* const* d_in, const int* in_sizes, int n_in,
                              void* d_out, int out_size, void* d_ws, size_t ws_size,
                              hipStream_t stream) {
  const int* ids = (const int*)d_in[0];
  const float* embedding = (const float*)d_in[1];
  const float* lm_head = (const float*)d_in[2];
  const float* F[11]; const float* Bp[11];
  for (int i = 0; i < 11; ++i) { F[i] = (const float*)d_in[3 + i]; Bp[i] = (const float*)d_in[14 + i]; }
  // 0 in_proj, 1 conv_w, 2 conv_b, 3 x_proj, 4 dt_w, 5 dt_b, 6 A_log, 7 Dp, 8 out_proj, 9 norm_w, 10 norm_f

  char* ws = (char*)d_ws;
  size_t off = 0;
  auto AL = [&](size_t bytes) { size_t o = off; off += (bytes + 255) & ~(size_t)255; return o; };
  size_t o_win  = AL((size_t)2 * NLAYER * E2_ * DMODEL * 2);
  size_t o_wxp  = AL((size_t)2 * NLAYER * DBCN * DI_ * 2);
  size_t o_wdtw = AL((size_t)2 * NLAYER * DI_ * KPAD * 2);
  size_t o_wout = AL((size_t)2 * NLAYER * DMODEL * DI_ * 2);
  size_t o_wlm  = AL((size_t)DMODEL * DI_ * 2);
  size_t o_wemb = AL((size_t)VOCAB * DMODEL * 2);
  size_t o_dtb  = AL((size_t)2 * NLAYER * DI_ * 4);
  size_t o_res  = AL((size_t)2 * L_SEQ * DMODEL * 4);
  size_t o_hid  = AL((size_t)2 * L_SEQ * DMODEL * 4);
  size_t o_hn   = AL((size_t)2 * L_SEQ * DMODEL * 2);
  size_t o_xz   = AL((size_t)2 * L_SEQ * E2_ * 4);
  size_t o_xc   = AL((size_t)2 * L_SEQ * DI_ * 4);
  size_t o_xcb  = AL((size_t)2 * L_SEQ * DI_ * 2);
  size_t o_dbc  = AL((size_t)2 * L_SEQ * DBCN * 4);
  size_t o_dbcb = AL((size_t)2 * L_SEQ * KPAD * 2);
  size_t o_dlt  = AL((size_t)2 * L_SEQ * DI_ * 4);
  size_t o_ys   = AL((size_t)2 * L_SEQ * DI_ * 4);
  size_t o_yb   = AL((size_t)2 * L_SEQ * DI_ * 2);
  size_t o_hcat = AL((size_t)L_SEQ * DI_ * 2);
  size_t o_proj = AL((size_t)L_SEQ * DMODEL * 2);
  if (ws_size < off) return;

  unsigned short* w_in  = (unsigned short*)(ws + o_win);
  unsigned short* w_xp  = (unsigned short*)(ws + o_wxp);
  unsigned short* w_dtw = (unsigned short*)(ws + o_wdtw);
  unsigned short* w_out = (unsigned short*)(ws + o_wout);
  unsigned short* w_lm  = (unsigned short*)(ws + o_wlm);
  unsigned short* w_emb = (unsigned short*)(ws + o_wemb);
  float* dtb = (float*)(ws + o_dtb);
  float* res = (float*)(ws + o_res);
  float* hid = (float*)(ws + o_hid);
  unsigned short* hn = (unsigned short*)(ws + o_hn);
  float* xz = (float*)(ws + o_xz);
  float* xc = (float*)(ws + o_xc);
  unsigned short* xcb = (unsigned short*)(ws + o_xcb);
  float* dbc = (float*)(ws + o_dbc);
  unsigned short* dbcb = (unsigned short*)(ws + o_dbcb);
  float* dlt = (float*)(ws + o_dlt);
  float* ysb = (float*)(ws + o_ys);
  unsigned short* yb = (unsigned short*)(ws + o_yb);
  unsigned short* hcat = (unsigned short*)(ws + o_hcat);
  unsigned short* projb = (unsigned short*)(ws + o_proj);
  float* logits = (float*)d_out;

  // ---- weight conversions ----
  {
    long n = (long)NLAYER * E2_ * DMODEL;
    cvt2_kernel<<<dim3((n + 255) / 256, 1, 2), 256, 0, stream>>>(F[0], Bp[0], w_in, n);
    n = (long)NLAYER * DBCN * DI_;
    cvt2_kernel<<<dim3((n + 255) / 256, 1, 2), 256, 0, stream>>>(F[3], Bp[3], w_xp, n);
    cvtdtw_kernel<<<dim3(((long)NLAYER * DI_ * KPAD + 255) / 256, 1, 2), 256, 0, stream>>>(F[4], Bp[4], w_dtw);
    n = (long)NLAYER * DMODEL * DI_;
    cvt2_kernel<<<dim3((n + 255) / 256, 1, 2), 256, 0, stream>>>(F[8], Bp[8], w_out, n);
    n = (long)DMODEL * DI_;
    cvt1_kernel<<<dim3((n + 255) / 256, 1, 1), 256, 0, stream>>>(lm_head, w_lm, n);
    n = (long)VOCAB * DMODEL;
    cvt1_kernel<<<dim3((n + 255) / 256, 1, 1), 256, 0, stream>>>(embedding, w_emb, n);
    hipMemcpyAsync(dtb, F[5], (size_t)NLAYER * DI_ * 4, hipMemcpyDeviceToDevice, stream);
    hipMemcpyAsync(dtb + NLAYER * DI_, Bp[5], (size_t)NLAYER * DI_ * 4, hipMemcpyDeviceToDevice, stream);
  }

  gather_kernel<<<dim3(L_SEQ * DMODEL / 256, 1, 2), 256, 0, stream>>>(ids, embedding, res);

  for (int layer = 0; layer < NLAYER; ++layer) {
    addnorm_kernel<<<dim3(L_SEQ, 1, 2), 256, 0, stream>>>(
        res, layer ? hid : nullptr, F[9], Bp[9], layer * DMODEL, hn);
    // xz = hn @ in_proj^T  (M=2048, N=3072, K=768)
    gemm_bt<0><<<dim3(E2_ / 128, L_SEQ / 128, 2), 256, 0, stream>>>(
        hn, (long)L_SEQ * DMODEL,
        w_in + (size_t)layer * E2_ * DMODEL, (long)NLAYER * E2_ * DMODEL,
        xz, nullptr, (long)L_SEQ * E2_, L_SEQ, E2_, DMODEL, nullptr, 0);
    conv_kernel<<<dim3(L_SEQ * DI_ / 256, 1, 2), 256, 0, stream>>>(
        xz, F[1], Bp[1], F[2], Bp[2], layer, xc, xcb);
    // dbc = x @ x_proj^T (M=2048, N=80, K=1536)
    gemm_bt<0><<<dim3(1, L_SEQ / 128, 2), 256, 0, stream>>>(
        xcb, (long)L_SEQ * DI_,
        w_xp + (size_t)layer * DBCN * DI_, (long)NLAYER * DBCN * DI_,
        dbc, nullptr, (long)L_SEQ * DBCN, L_SEQ, DBCN, DI_, nullptr, 0);
    dbcpad_kernel<<<dim3(L_SEQ * KPAD / 256, 1, 2), 256, 0, stream>>>(dbc, dbcb);
    // delta = softplus(dbc[:, :48] @ dt_w^T + dt_b) (M=2048, N=1536, K=64)
    gemm_bt<1><<<dim3(DI_ / 128, L_SEQ / 128, 2), 256, 0, stream>>>(
        dbcb, (long)L_SEQ * KPAD,
        w_dtw + (size_t)layer * DI_ * KPAD, (long)NLAYER * DI_ * KPAD,
        dlt, nullptr, (long)L_SEQ * DI_, L_SEQ, DI_, KPAD,
        dtb + layer * DI_, (long)NLAYER * DI_);
    scan_kernel<<<dim3(DI_ / 16, 1, 2), 256, 0, stream>>>(
        dlt, xc, dbc, F[6], Bp[6], layer * DI_ * SSTATE, ysb);
    ycomb_kernel<<<dim3(L_SEQ * DI_ / 256, 1, 2), 256, 0, stream>>>(
        ysb, xc, xz, F[7], Bp[7], layer * DI_, yb);
    // hid = y @ out_proj^T (M=2048, N=768, K=1536)
    gemm_bt<0><<<dim3(DMODEL / 128, L_SEQ / 128, 2), 256, 0, stream>>>(
        yb, (long)L_SEQ * DI_,
        w_out + (size_t)layer * DMODEL * DI_, (long)NLAYER * DMODEL * DI_,
        hid, nullptr, (long)L_SEQ * DMODEL, L_SEQ, DMODEL, DI_, nullptr, 0);
  }

  finalcat_kernel<<<dim3(L_SEQ, 1, 2), 256, 0, stream>>>(res, hid, F[10], Bp[10], hcat);
  // proj = hcat @ lm_head^T (M=2048, N=768, K=1536) -> bf16
  gemm_bt<2><<<dim3(DMODEL / 128, L_SEQ / 128, 1), 256, 0, stream>>>(
      hcat, 0, w_lm, 0, nullptr, projb, 0, L_SEQ, DMODEL, DI_, nullptr, 0);
  // logits = proj @ embedding^T (M=2048, N=32000, K=768) -> f32 d_out
  gemm_bt<0><<<dim3(VOCAB / 128, L_SEQ / 128, 1), 256, 0, stream>>>(
      projb, 0, w_emb, 0, logits, nullptr, 0, L_SEQ, VOCAB, DMODEL, nullptr, 0);
}

// Round 2
// 1105.820 us; speedup vs baseline: 1.4855x; 1.4855x over previous
//
#include <hip/hip_runtime.h>
#include <hip/hip_bf16.h>
#include <stdint.h>

#define L_SEQ 2048
#define DMODEL 768
#define DI_ 1536
#define E2_ 3072
#define NLAYER 2
#define SSTATE 16
#define DBCN 80
#define KPAD 64
#define VOCAB 32000
#define NCHUNK 32
#define TCH 64

typedef __bf16 bf16x8 __attribute__((ext_vector_type(8)));
typedef float f32x4 __attribute__((ext_vector_type(4)));

__device__ __forceinline__ unsigned short f2bf(float x) {
  union { float f; uint32_t u; } v; v.f = x;
  uint32_t r = (v.u + 0x7FFFu + ((v.u >> 16) & 1u)) >> 16;
  return (unsigned short)r;
}
__device__ __forceinline__ float siluf_(float x) { return x / (1.f + __expf(-x)); }
__device__ __forceinline__ float softplusf_(float x) {
  return fmaxf(x, 0.f) + log1pf(__expf(-fabsf(x)));
}

// ---------------- weight conversion ----------------
__global__ __launch_bounds__(256) void cvt2_kernel(const float* __restrict__ f,
                                                   const float* __restrict__ b,
                                                   unsigned short* __restrict__ dst, long n) {
  long i = (long)blockIdx.x * 256 + threadIdx.x;
  if (i >= n) return;
  const float* s = blockIdx.z ? b : f;
  dst[(long)blockIdx.z * n + i] = f2bf(s[i]);
}
__global__ __launch_bounds__(256) void cvt1_kernel(const float* __restrict__ s,
                                                   unsigned short* __restrict__ dst, long n) {
  long i = (long)blockIdx.x * 256 + threadIdx.x;
  if (i >= n) return;
  dst[i] = f2bf(s[i]);
}
// dt_w (NLAYER*DI_ rows x 48) -> padded (x64)
__global__ __launch_bounds__(256) void cvtdtw_kernel(const float* __restrict__ f,
                                                     const float* __restrict__ b,
                                                     unsigned short* __restrict__ dst) {
  long n = (long)NLAYER * DI_ * KPAD;
  long i = (long)blockIdx.x * 256 + threadIdx.x;
  if (i >= n) return;
  long r = i >> 6; int c = (int)(i & 63);
  const float* s = blockIdx.z ? b : f;
  dst[(long)blockIdx.z * n + i] = f2bf(c < 48 ? s[r * 48 + c] : 0.f);
}

// ---------------- embedding gather (+flip for dir=1) ----------------
__global__ __launch_bounds__(256) void gather_kernel(const int* __restrict__ ids,
                                                     const float* __restrict__ emb,
                                                     float* __restrict__ res) {
  int idx = blockIdx.x * 256 + threadIdx.x;           // over L*D
  int z = blockIdx.z;
  int l = idx / DMODEL, c = idx % DMODEL;
  int srcl = z ? (L_SEQ - 1 - l) : l;
  res[(size_t)z * L_SEQ * DMODEL + idx] = emb[(size_t)ids[srcl] * DMODEL + c];
}

// ---------------- residual add + rmsnorm -> bf16 ----------------
__global__ __launch_bounds__(256) void addnorm_kernel(float* __restrict__ res,
                                                      const float* __restrict__ hid,
                                                      const float* __restrict__ wf,
                                                      const float* __restrict__ wb, int woff,
                                                      unsigned short* __restrict__ out) {
  int z = blockIdx.z, l = blockIdx.x, t = threadIdx.x;
  const float* w = (z ? wb : wf) + woff;
  size_t base = ((size_t)z * L_SEQ + l) * DMODEL;
  float v[3]; float ss = 0.f;
  #pragma unroll
  for (int i = 0; i < 3; ++i) {
    int c = t + i * 256;
    float x = res[base + c];
    if (hid) { x += hid[base + c]; res[base + c] = x; }
    v[i] = x; ss += x * x;
  }
  #pragma unroll
  for (int m = 32; m; m >>= 1) ss += __shfl_xor(ss, m);
  __shared__ float red[4];
  if ((t & 63) == 0) red[t >> 6] = ss;
  __syncthreads();
  ss = red[0] + red[1] + red[2] + red[3];
  float inv = rsqrtf(ss * (1.f / DMODEL) + 1e-5f);
  #pragma unroll
  for (int i = 0; i < 3; ++i) {
    int c = t + i * 256;
    out[base + c] = f2bf(v[i] * inv * w[c]);
  }
}

// final rmsnorm(hid+res) -> bf16 into hcat with flip+col-offset for dir=1
__global__ __launch_bounds__(256) void finalcat_kernel(const float* __restrict__ res,
                                                       const float* __restrict__ hid,
                                                       const float* __restrict__ wf,
                                                       const float* __restrict__ wb,
                                                       unsigned short* __restrict__ hcat) {
  int z = blockIdx.z, l = blockIdx.x, t = threadIdx.x;
  const float* w = z ? wb : wf;
  size_t base = ((size_t)z * L_SEQ + l) * DMODEL;
  float v[3]; float ss = 0.f;
  #pragma unroll
  for (int i = 0; i < 3; ++i) {
    int c = t + i * 256;
    float x = res[base + c] + hid[base + c];
    v[i] = x; ss += x * x;
  }
  #pragma unroll
  for (int m = 32; m; m >>= 1) ss += __shfl_xor(ss, m);
  __shared__ float red[4];
  if ((t & 63) == 0) red[t >> 6] = ss;
  __syncthreads();
  ss = red[0] + red[1] + red[2] + red[3];
  float inv = rsqrtf(ss * (1.f / DMODEL) + 1e-5f);
  int outl = z ? (L_SEQ - 1 - l) : l;
  #pragma unroll
  for (int i = 0; i < 3; ++i) {
    int c = t + i * 256;
    hcat[(size_t)outl * DI_ + z * DMODEL + c] = f2bf(v[i] * inv * w[c]);
  }
}

// ---------------- circular depthwise conv K=4 + silu ----------------
__global__ __launch_bounds__(256) void conv_kernel(const float* __restrict__ xz,
                                                   const float* __restrict__ cwf,
                                                   const float* __restrict__ cwb,
                                                   const float* __restrict__ cbf,
                                                   const float* __restrict__ cbb, int layer,
                                                   float* __restrict__ xf,
                                                   unsigned short* __restrict__ xbf) {
  int z = blockIdx.z;
  int idx = blockIdx.x * 256 + threadIdx.x;           // over L*DI
  int l = idx / DI_, d = idx % DI_;
  const float* cw = (z ? cwb : cwf) + layer * DI_ * 4;
  const float* cb = (z ? cbb : cbf) + layer * DI_;
  const float* xzp = xz + (size_t)z * L_SEQ * E2_;
  float acc = cb[d];
  #pragma unroll
  for (int k = 0; k < 4; ++k) {
    int ls = (l + k - 3 + L_SEQ) & (L_SEQ - 1);
    acc += cw[d * 4 + k] * xzp[(size_t)ls * E2_ + d];
  }
  float s = siluf_(acc);
  size_t o = (size_t)z * L_SEQ * DI_ + idx;
  xf[o] = s;
  xbf[o] = f2bf(s);
}

// ---------------- dbc f32 -> bf16, pad 48->64 ----------------
__global__ __launch_bounds__(256) void dbcpad_kernel(const float* __restrict__ dbc,
                                                     unsigned short* __restrict__ out) {
  int z = blockIdx.z;
  int idx = blockIdx.x * 256 + threadIdx.x;           // over L*KPAD
  int l = idx >> 6, c = idx & 63;
  float v = (c < 48) ? dbc[(size_t)z * L_SEQ * DBCN + (size_t)l * DBCN + c] : 0.f;
  out[(size_t)z * L_SEQ * KPAD + idx] = f2bf(v);
}

// ---------------- chunk-parallel selective scan ----------------
// Phase A: per (z, d-block, chunk): local scan h_in=0 -> store P=exp(A*sum dlt), Q=h_end
// layout of P/Q/hin: [z][c][d][s]
__global__ __launch_bounds__(256) void scanA_kernel(const float* __restrict__ delta,
                                                    const float* __restrict__ u,
                                                    const float* __restrict__ dbc,
                                                    const float* __restrict__ Af,
                                                    const float* __restrict__ Ab, int aoff,
                                                    float* __restrict__ Pg,
                                                    float* __restrict__ Qg) {
  const int z = blockIdx.z;
  const int d0 = blockIdx.x * 16;
  const int c = blockIdx.y;
  const int tid = threadIdx.x;
  const int s = tid & 15;
  const int g = tid >> 4;
  const int d = d0 + g;
  __shared__ float sd[16 * 65], su2[16 * 65], sb2[16 * 65];
  const size_t zo = (size_t)z * L_SEQ * DI_;
  const float* dl = delta + zo;
  const float* ul = u + zo;
  const float* bc = dbc + (size_t)z * L_SEQ * DBCN;
  const float A = -__expf(((z ? Ab : Af) + aoff)[d * SSTATE + s]);
  const int l0 = c * TCH;
  #pragma unroll
  for (int i = 0; i < 4; ++i) {
    int idx = tid + i * 256;
    int di = idx & 15, li = idx >> 4;
    size_t gl = (size_t)(l0 + li);
    sd[di * 65 + li]  = dl[gl * DI_ + d0 + di];
    su2[di * 65 + li] = ul[gl * DI_ + d0 + di];
    sb2[di * 65 + li] = bc[gl * DBCN + 48 + di];
  }
  __syncthreads();
  float h = 0.f, sda = 0.f;
  #pragma unroll 4
  for (int t = 0; t < TCH; ++t) {
    float dlt = sd[g * 65 + t];
    float uu  = su2[g * 65 + t];
    float bb  = sb2[s * 65 + t];
    float a = __expf(dlt * A);
    h = a * h + dlt * uu * bb;
    sda += dlt;
  }
  size_t o = ((size_t)(z * NCHUNK + c) * DI_ + d) * SSTATE + s;
  Pg[o] = __expf(sda * A);
  Qg[o] = h;
}

// Phase B: sequential combine over chunks per (z,d,s); emits h_in per chunk
__global__ __launch_bounds__(256) void scanB_kernel(const float* __restrict__ Pg,
                                                    const float* __restrict__ Qg,
                                                    float* __restrict__ hin) {
  int idx = blockIdx.x * 256 + threadIdx.x;   // over 2*DI*16
  int z = idx / (DI_ * SSTATE);
  int r = idx % (DI_ * SSTATE);
  float h = 0.f;
  #pragma unroll
  for (int c = 0; c < NCHUNK; ++c) {
    size_t o = (size_t)(z * NCHUNK + c) * DI_ * SSTATE + r;
    hin[o] = h;
    h = Pg[o] * h + Qg[o];
  }
}

// Phase C: local scan with correct h_in, produce y, fuse (y + Dp*x)*silu(z) -> bf16
__global__ __launch_bounds__(256) void scanC_kernel(const float* __restrict__ delta,
                                                    const float* __restrict__ u,
                                                    const float* __restrict__ dbc,
                                                    const float* __restrict__ xz,
                                                    const float* __restrict__ Af,
                                                    const float* __restrict__ Ab, int aoff,
                                                    const float* __restrict__ Dpf,
                                                    const float* __restrict__ Dpb, int doff,
                                                    const float* __restrict__ hin,
                                                    unsigned short* __restrict__ yb) {
  const int z = blockIdx.z;
  const int d0 = blockIdx.x * 16;
  const int c = blockIdx.y;
  const int tid = threadIdx.x;
  const int s = tid & 15;
  const int g = tid >> 4;
  const int d = d0 + g;
  __shared__ float sd[16 * 65], su2[16 * 65], sb2[16 * 65], sc2[16 * 65], sy2[16 * 65];
  const size_t zo = (size_t)z * L_SEQ * DI_;
  const float* dl = delta + zo;
  const float* ul = u + zo;
  const float* bc = dbc + (size_t)z * L_SEQ * DBCN;
  const float A = -__expf(((z ? Ab : Af) + aoff)[d * SSTATE + s]);
  const int l0 = c * TCH;
  #pragma unroll
  for (int i = 0; i < 4; ++i) {
    int idx = tid + i * 256;
    int di = idx & 15, li = idx >> 4;
    size_t gl = (size_t)(l0 + li);
    sd[di * 65 + li]  = dl[gl * DI_ + d0 + di];
    su2[di * 65 + li] = ul[gl * DI_ + d0 + di];
    sb2[di * 65 + li] = bc[gl * DBCN + 48 + di];
    sc2[di * 65 + li] = bc[gl * DBCN + 64 + di];
  }
  __syncthreads();
  float h = hin[((size_t)(z * NCHUNK + c) * DI_ + d) * SSTATE + s];
  for (int t = 0; t < TCH; t += 2) {
    float dlt0 = sd[g * 65 + t],     uu0 = su2[g * 65 + t];
    float bb0  = sb2[s * 65 + t],    cc0 = sc2[s * 65 + t];
    float dlt1 = sd[g * 65 + t + 1], uu1 = su2[g * 65 + t + 1];
    float bb1  = sb2[s * 65 + t + 1], cc1 = sc2[s * 65 + t + 1];
    float a0 = __expf(dlt0 * A); h = a0 * h + dlt0 * uu0 * bb0; float p0 = h * cc0;
    float a1 = __expf(dlt1 * A); h = a1 * h + dlt1 * uu1 * bb1; float p1 = h * cc1;
    p0 += __shfl_xor(p0, 1); p1 += __shfl_xor(p1, 1);
    p0 += __shfl_xor(p0, 2); p1 += __shfl_xor(p1, 2);
    p0 += __shfl_xor(p0, 4); p1 += __shfl_xor(p1, 4);
    p0 += __shfl_xor(p0, 8); p1 += __shfl_xor(p1, 8);
    if (s == 0) { sy2[g * 65 + t] = p0; sy2[g * 65 + t + 1] = p1; }
  }
  __syncthreads();
  const float* Dp = (z ? Dpb : Dpf) + doff;
  #pragma unroll
  for (int i = 0; i < 4; ++i) {
    int idx = tid + i * 256;
    int di = idx & 15, li = idx >> 4;
    int l = l0 + li;
    float y = sy2[di * 65 + li];
    float uu = su2[di * 65 + li];
    float zz = xz[(size_t)z * L_SEQ * E2_ + (size_t)l * E2_ + DI_ + d0 + di];
    float v = (y + Dp[d0 + di] * uu) * siluf_(zz);
    yb[zo + (size_t)l * DI_ + d0 + di] = f2bf(v);
  }
}

// ---------------- generic bf16 MFMA GEMM: C[M,N] = A[M,K] * B[N,K]^T ----------------
// EPI: 0 = f32 store, 1 = softplus(v + bias[col]) f32 store, 2 = bf16 store
template <int EPI>
__global__ __launch_bounds__(256)
void gemm_bt(const unsigned short* __restrict__ Ag, long sAz,
             const unsigned short* __restrict__ Bg, long sBz,
             float* __restrict__ Cf, unsigned short* __restrict__ Cb, long sCz,
             int M, int N, int K,
             const float* __restrict__ bias, long sBiasz) {
  __shared__ __align__(16) unsigned short sA[128 * 64];
  __shared__ __align__(16) unsigned short sB[128 * 64];
  const int tid = threadIdx.x;
  const int lane = tid & 63;
  const int wv = tid >> 6;
  const int z = blockIdx.z;
  const int m0 = blockIdx.y * 128;
  const int n0 = blockIdx.x * 128;
  const unsigned short* A = Ag + (size_t)z * sAz;
  const unsigned short* B = Bg + (size_t)z * sBz;
  const int wm = (wv >> 1) * 64;
  const int wn = (wv & 1) * 64;
  const int lr = lane & 15;
  const int lk8 = (lane >> 4) * 8;

  f32x4 acc[4][4] = {};

  for (int k0 = 0; k0 < K; k0 += 64) {
    #pragma unroll
    for (int i = 0; i < 4; ++i) {
      int c = tid + i * 256;
      int row = c >> 3;
      int kc = (c & 7) * 8;
      int ra = m0 + row; if (ra > M - 1) ra = M - 1;
      int rb = n0 + row; if (rb > N - 1) rb = N - 1;
      uint4 va = *(const uint4*)(A + (size_t)ra * K + (k0 + kc));
      uint4 vb = *(const uint4*)(B + (size_t)rb * K + (k0 + kc));
      *(uint4*)(sA + row * 64 + kc) = va;
      *(uint4*)(sB + row * 64 + kc) = vb;
    }
    __syncthreads();
    #pragma unroll
    for (int kk = 0; kk < 64; kk += 32) {
      bf16x8 af[4], bfr[4];
      #pragma unroll
      for (int i = 0; i < 4; ++i) {
        af[i]  = *(const bf16x8*)(sA + (wm + i * 16 + lr) * 64 + kk + lk8);
        bfr[i] = *(const bf16x8*)(sB + (wn + i * 16 + lr) * 64 + kk + lk8);
      }
      #pragma unroll
      for (int mi = 0; mi < 4; ++mi)
        #pragma unroll
        for (int ni = 0; ni < 4; ++ni)
          acc[mi][ni] = __builtin_amdgcn_mfma_f32_16x16x32_bf16(af[mi], bfr[ni], acc[mi][ni], 0, 0, 0);
    }
    __syncthreads();
  }

  const int orow0 = m0 + wm + (lane >> 4) * 4;
  const int ocol0 = n0 + wn + lr;
  #pragma unroll
  for (int mi = 0; mi < 4; ++mi) {
    #pragma unroll
    for (int ni = 0; ni < 4; ++ni) {
      int col = ocol0 + ni * 16;
      if (col >= N) continue;
      #pragma unroll
      for (int j = 0; j < 4; ++j) {
        int row = orow0 + mi * 16 + j;
        if (row >= M) continue;
        float v = acc[mi][ni][j];
        if constexpr (EPI == 1) v = softplusf_(v + bias[(size_t)z * sBiasz + col]);
        if constexpr (EPI == 2) {
          Cb[(size_t)z * sCz + (size_t)row * N + col] = f2bf(v);
        } else {
          Cf[(size_t)z * sCz + (size_t)row * N + col] = v;
        }
      }
    }
  }
}

// ==================== host launcher ====================
extern "C" void kernel_launch(void* const* d_in, const int* in_sizes, int n_in,
                              void* d_out, int out_size, void* d_ws, size_t ws_size,
                              hipStream_t stream) {
  const int* ids = (const int*)d_in[0];
  const float* embedding = (const float*)d_in[1];
  const float* lm_head = (const float*)d_in[2];
  const float* F[11]; const float* Bp[11];
  for (int i = 0; i < 11; ++i) { F[i] = (const float*)d_in[3 + i]; Bp[i] = (const float*)d_in[14 + i]; }
  // 0 in_proj, 1 conv_w, 2 conv_b, 3 x_proj, 4 dt_w, 5 dt_b, 6 A_log, 7 Dp, 8 out_proj, 9 norm_w, 10 norm_f

  char* ws = (char*)d_ws;
  size_t off = 0;
  auto AL = [&](size_t bytes) { size_t o = off; off += (bytes + 255) & ~(size_t)255; return o; };
  size_t o_win  = AL((size_t)2 * NLAYER * E2_ * DMODEL * 2);
  size_t o_wxp  = AL((size_t)2 * NLAYER * DBCN * DI_ * 2);
  size_t o_wdtw = AL((size_t)2 * NLAYER * DI_ * KPAD * 2);
  size_t o_wout = AL((size_t)2 * NLAYER * DMODEL * DI_ * 2);
  size_t o_wlm  = AL((size_t)DMODEL * DI_ * 2);
  size_t o_wemb = AL((size_t)VOCAB * DMODEL * 2);
  size_t o_dtb  = AL((size_t)2 * NLAYER * DI_ * 4);
  size_t o_res  = AL((size_t)2 * L_SEQ * DMODEL * 4);
  size_t o_hid  = AL((size_t)2 * L_SEQ * DMODEL * 4);
  size_t o_hn   = AL((size_t)2 * L_SEQ * DMODEL * 2);
  size_t o_xz   = AL((size_t)2 * L_SEQ * E2_ * 4);
  size_t o_xc   = AL((size_t)2 * L_SEQ * DI_ * 4);
  size_t o_xcb  = AL((size_t)2 * L_SEQ * DI_ * 2);
  size_t o_dbc  = AL((size_t)2 * L_SEQ * DBCN * 4);
  size_t o_dbcb = AL((size_t)2 * L_SEQ * KPAD * 2);
  size_t o_dlt  = AL((size_t)2 * L_SEQ * DI_ * 4);
  size_t o_P    = AL((size_t)2 * NCHUNK * DI_ * SSTATE * 4);
  size_t o_Q    = AL((size_t)2 * NCHUNK * DI_ * SSTATE * 4);
  size_t o_hin  = AL((size_t)2 * NCHUNK * DI_ * SSTATE * 4);
  size_t o_yb   = AL((size_t)2 * L_SEQ * DI_ * 2);
  size_t o_hcat = AL((size_t)L_SEQ * DI_ * 2);
  size_t o_proj = AL((size_t)L_SEQ * DMODEL * 2);
  if (ws_size < off) return;

  unsigned short* w_in  = (unsigned short*)(ws + o_win);
  unsigned short* w_xp  = (unsigned short*)(ws + o_wxp);
  unsigned short* w_dtw = (unsigned short*)(ws + o_wdtw);
  unsigned short* w_out = (unsigned short*)(ws + o_wout);
  unsigned short* w_lm  = (unsigned short*)(ws + o_wlm);
  unsigned short* w_emb = (unsigned short*)(ws + o_wemb);
  float* dtb = (float*)(ws + o_dtb);
  float* res = (float*)(ws + o_res);
  float* hid = (float*)(ws + o_hid);
  unsigned short* hn = (unsigned short*)(ws + o_hn);
  float* xz = (float*)(ws + o_xz);
  float* xc = (float*)(ws + o_xc);
  unsigned short* xcb = (unsigned short*)(ws + o_xcb);
  float* dbc = (float*)(ws + o_dbc);
  unsigned short* dbcb = (unsigned short*)(ws + o_dbcb);
  float* dlt = (float*)(ws + o_dlt);
  float* Pg  = (float*)(ws + o_P);
  float* Qg  = (float*)(ws + o_Q);
  float* hing = (float*)(ws + o_hin);
  unsigned short* yb = (unsigned short*)(ws + o_yb);
  unsigned short* hcat = (unsigned short*)(ws + o_hcat);
  unsigned short* projb = (unsigned short*)(ws + o_proj);
  float* logits = (float*)d_out;

  // ---- weight conversions ----
  {
    long n = (long)NLAYER * E2_ * DMODEL;
    cvt2_kernel<<<dim3((n + 255) / 256, 1, 2), 256, 0, stream>>>(F[0], Bp[0], w_in, n);
    n = (long)NLAYER * DBCN * DI_;
    cvt2_kernel<<<dim3((n + 255) / 256, 1, 2), 256, 0, stream>>>(F[3], Bp[3], w_xp, n);
    cvtdtw_kernel<<<dim3(((long)NLAYER * DI_ * KPAD + 255) / 256, 1, 2), 256, 0, stream>>>(F[4], Bp[4], w_dtw);
    n = (long)NLAYER * DMODEL * DI_;
    cvt2_kernel<<<dim3((n + 255) / 256, 1, 2), 256, 0, stream>>>(F[8], Bp[8], w_out, n);
    n = (long)DMODEL * DI_;
    cvt1_kernel<<<dim3((n + 255) / 256, 1, 1), 256, 0, stream>>>(lm_head, w_lm, n);
    n = (long)VOCAB * DMODEL;
    cvt1_kernel<<<dim3((n + 255) / 256, 1, 1), 256, 0, stream>>>(embedding, w_emb, n);
    hipMemcpyAsync(dtb, F[5], (size_t)NLAYER * DI_ * 4, hipMemcpyDeviceToDevice, stream);
    hipMemcpyAsync(dtb + NLAYER * DI_, Bp[5], (size_t)NLAYER * DI_ * 4, hipMemcpyDeviceToDevice, stream);
  }

  gather_kernel<<<dim3(L_SEQ * DMODEL / 256, 1, 2), 256, 0, stream>>>(ids, embedding, res);

  for (int layer = 0; layer < NLAYER; ++layer) {
    addnorm_kernel<<<dim3(L_SEQ, 1, 2), 256, 0, stream>>>(
        res, layer ? hid : nullptr, F[9], Bp[9], layer * DMODEL, hn);
    // xz = hn @ in_proj^T  (M=2048, N=3072, K=768)
    gemm_bt<0><<<dim3(E2_ / 128, L_SEQ / 128, 2), 256, 0, stream>>>(
        hn, (long)L_SEQ * DMODEL,
        w_in + (size_t)layer * E2_ * DMODEL, (long)NLAYER * E2_ * DMODEL,
        xz, nullptr, (long)L_SEQ * E2_, L_SEQ, E2_, DMODEL, nullptr, 0);
    conv_kernel<<<dim3(L_SEQ * DI_ / 256, 1, 2), 256, 0, stream>>>(
        xz, F[1], Bp[1], F[2], Bp[2], layer, xc, xcb);
    // dbc = x @ x_proj^T (M=2048, N=80, K=1536)
    gemm_bt<0><<<dim3(1, L_SEQ / 128, 2), 256, 0, stream>>>(
        xcb, (long)L_SEQ * DI_,
        w_xp + (size_t)layer * DBCN * DI_, (long)NLAYER * DBCN * DI_,
        dbc, nullptr, (long)L_SEQ * DBCN, L_SEQ, DBCN, DI_, nullptr, 0);
    dbcpad_kernel<<<dim3(L_SEQ * KPAD / 256, 1, 2), 256, 0, stream>>>(dbc, dbcb);
    // delta = softplus(dbc[:, :48] @ dt_w^T + dt_b) (M=2048, N=1536, K=64)
    gemm_bt<1><<<dim3(DI_ / 128, L_SEQ / 128, 2), 256, 0, stream>>>(
        dbcb, (long)L_SEQ * KPAD,
        w_dtw + (size_t)layer * DI_ * KPAD, (long)NLAYER * DI_ * KPAD,
        dlt, nullptr, (long)L_SEQ * DI_, L_SEQ, DI_, KPAD,
        dtb + layer * DI_, (long)NLAYER * DI_);
    // chunk-parallel scan (A: local scans, B: combine, C: replay + fused ycomb)
    scanA_kernel<<<dim3(DI_ / 16, NCHUNK, 2), 256, 0, stream>>>(
        dlt, xc, dbc, F[6], Bp[6], layer * DI_ * SSTATE, Pg, Qg);
    scanB_kernel<<<dim3(2 * DI_ * SSTATE / 256, 1, 1), 256, 0, stream>>>(Pg, Qg, hing);
    scanC_kernel<<<dim3(DI_ / 16, NCHUNK, 2), 256, 0, stream>>>(
        dlt, xc, dbc, xz, F[6], Bp[6], layer * DI_ * SSTATE,
        F[7], Bp[7], layer * DI_, hing, yb);
    // hid = y @ out_proj^T (M=2048, N=768, K=1536)
    gemm_bt<0><<<dim3(DMODEL / 128, L_SEQ / 128, 2), 256, 0, stream>>>(
        yb, (long)L_SEQ * DI_,
        w_out + (size_t)layer * DMODEL * DI_, (long)NLAYER * DMODEL * DI_,
        hid, nullptr, (long)L_SEQ * DMODEL, L_SEQ, DMODEL, DI_, nullptr, 0);
  }

  finalcat_kernel<<<dim3(L_SEQ, 1, 2), 256, 0, stream>>>(res, hid, F[10], Bp[10], hcat);
  // proj = hcat @ lm_head^T (M=2048, N=768, K=1536) -> bf16
  gemm_bt<2><<<dim3(DMODEL / 128, L_SEQ / 128, 1), 256, 0, stream>>>(
      hcat, 0, w_lm, 0, nullptr, projb, 0, L_SEQ, DMODEL, DI_, nullptr, 0);
  // logits = proj @ embedding^T (M=2048, N=32000, K=768) -> f32 d_out
  gemm_bt<0><<<dim3(VOCAB / 128, L_SEQ / 128, 1), 256, 0, stream>>>(
      projb, 0, w_emb, 0, logits, nullptr, 0, L_SEQ, VOCAB, DMODEL, nullptr, 0);
}

// Round 3
// 1021.879 us; speedup vs baseline: 1.6075x; 1.0821x over previous
//
#include <hip/hip_runtime.h>
#include <hip/hip_bf16.h>
#include <stdint.h>

#define L_SEQ 2048
#define DMODEL 768
#define DI_ 1536
#define E2_ 3072
#define NLAYER 2
#define SSTATE 16
#define DBCN 80
#define KPAD 64
#define VOCAB 32000
#define NCHUNK 32
#define TCH 64

typedef __bf16 bf16x8 __attribute__((ext_vector_type(8)));
typedef float f32x4 __attribute__((ext_vector_type(4)));

__device__ __forceinline__ unsigned short f2bf(float x) {
  union { float f; uint32_t u; } v; v.f = x;
  uint32_t r = (v.u + 0x7FFFu + ((v.u >> 16) & 1u)) >> 16;
  return (unsigned short)r;
}
__device__ __forceinline__ float siluf_(float x) { return x / (1.f + __expf(-x)); }
__device__ __forceinline__ float softplusf_(float x) {
  return fmaxf(x, 0.f) + log1pf(__expf(-fabsf(x)));
}

// ---------------- weight conversion (vectorized x4) ----------------
__global__ __launch_bounds__(256) void cvt2_kernel(const float* __restrict__ f,
                                                   const float* __restrict__ b,
                                                   unsigned short* __restrict__ dst, long n) {
  long i = ((long)blockIdx.x * 256 + threadIdx.x) * 4;
  if (i >= n) return;
  const float* s = blockIdx.z ? b : f;
  float4 v = *(const float4*)(s + i);
  ushort4 o; o.x = f2bf(v.x); o.y = f2bf(v.y); o.z = f2bf(v.z); o.w = f2bf(v.w);
  *(ushort4*)(dst + (long)blockIdx.z * n + i) = o;
}
__global__ __launch_bounds__(256) void cvt1_kernel(const float* __restrict__ s,
                                                   unsigned short* __restrict__ dst, long n) {
  long i = ((long)blockIdx.x * 256 + threadIdx.x) * 4;
  if (i >= n) return;
  float4 v = *(const float4*)(s + i);
  ushort4 o; o.x = f2bf(v.x); o.y = f2bf(v.y); o.z = f2bf(v.z); o.w = f2bf(v.w);
  *(ushort4*)(dst + i) = o;
}
// dt_w (NLAYER*DI_ rows x 48) -> padded (x64)
__global__ __launch_bounds__(256) void cvtdtw_kernel(const float* __restrict__ f,
                                                     const float* __restrict__ b,
                                                     unsigned short* __restrict__ dst) {
  long n = (long)NLAYER * DI_ * KPAD;
  long i = (long)blockIdx.x * 256 + threadIdx.x;
  if (i >= n) return;
  long r = i >> 6; int c = (int)(i & 63);
  const float* s = blockIdx.z ? b : f;
  dst[(long)blockIdx.z * n + i] = f2bf(c < 48 ? s[r * 48 + c] : 0.f);
}

// ---------------- embedding gather (+flip for dir=1) ----------------
__global__ __launch_bounds__(256) void gather_kernel(const int* __restrict__ ids,
                                                     const float* __restrict__ emb,
                                                     float* __restrict__ res) {
  int idx = blockIdx.x * 256 + threadIdx.x;           // over L*D
  int z = blockIdx.z;
  int l = idx / DMODEL, c = idx % DMODEL;
  int srcl = z ? (L_SEQ - 1 - l) : l;
  res[(size_t)z * L_SEQ * DMODEL + idx] = emb[(size_t)ids[srcl] * DMODEL + c];
}

// ---------------- residual add + rmsnorm -> bf16 ----------------
__global__ __launch_bounds__(256) void addnorm_kernel(float* __restrict__ res,
                                                      const float* __restrict__ hid,
                                                      const float* __restrict__ wf,
                                                      const float* __restrict__ wb, int woff,
                                                      unsigned short* __restrict__ out) {
  int z = blockIdx.z, l = blockIdx.x, t = threadIdx.x;
  const float* w = (z ? wb : wf) + woff;
  size_t base = ((size_t)z * L_SEQ + l) * DMODEL;
  float v[3]; float ss = 0.f;
  #pragma unroll
  for (int i = 0; i < 3; ++i) {
    int c = t + i * 256;
    float x = res[base + c];
    if (hid) { x += hid[base + c]; res[base + c] = x; }
    v[i] = x; ss += x * x;
  }
  #pragma unroll
  for (int m = 32; m; m >>= 1) ss += __shfl_xor(ss, m);
  __shared__ float red[4];
  if ((t & 63) == 0) red[t >> 6] = ss;
  __syncthreads();
  ss = red[0] + red[1] + red[2] + red[3];
  float inv = rsqrtf(ss * (1.f / DMODEL) + 1e-5f);
  #pragma unroll
  for (int i = 0; i < 3; ++i) {
    int c = t + i * 256;
    out[base + c] = f2bf(v[i] * inv * w[c]);
  }
}

// final rmsnorm(hid+res) -> bf16 into hcat with flip+col-offset for dir=1
__global__ __launch_bounds__(256) void finalcat_kernel(const float* __restrict__ res,
                                                       const float* __restrict__ hid,
                                                       const float* __restrict__ wf,
                                                       const float* __restrict__ wb,
                                                       unsigned short* __restrict__ hcat) {
  int z = blockIdx.z, l = blockIdx.x, t = threadIdx.x;
  const float* w = z ? wb : wf;
  size_t base = ((size_t)z * L_SEQ + l) * DMODEL;
  float v[3]; float ss = 0.f;
  #pragma unroll
  for (int i = 0; i < 3; ++i) {
    int c = t + i * 256;
    float x = res[base + c] + hid[base + c];
    v[i] = x; ss += x * x;
  }
  #pragma unroll
  for (int m = 32; m; m >>= 1) ss += __shfl_xor(ss, m);
  __shared__ float red[4];
  if ((t & 63) == 0) red[t >> 6] = ss;
  __syncthreads();
  ss = red[0] + red[1] + red[2] + red[3];
  float inv = rsqrtf(ss * (1.f / DMODEL) + 1e-5f);
  int outl = z ? (L_SEQ - 1 - l) : l;
  #pragma unroll
  for (int i = 0; i < 3; ++i) {
    int c = t + i * 256;
    hcat[(size_t)outl * DI_ + z * DMODEL + c] = f2bf(v[i] * inv * w[c]);
  }
}

// ---------------- circular depthwise conv K=4 + silu ----------------
__global__ __launch_bounds__(256) void conv_kernel(const float* __restrict__ xz,
                                                   const float* __restrict__ cwf,
                                                   const float* __restrict__ cwb,
                                                   const float* __restrict__ cbf,
                                                   const float* __restrict__ cbb, int layer,
                                                   float* __restrict__ xf,
                                                   unsigned short* __restrict__ xbf) {
  int z = blockIdx.z;
  int idx = blockIdx.x * 256 + threadIdx.x;           // over L*DI
  int l = idx / DI_, d = idx % DI_;
  const float* cw = (z ? cwb : cwf) + layer * DI_ * 4;
  const float* cb = (z ? cbb : cbf) + layer * DI_;
  const float* xzp = xz + (size_t)z * L_SEQ * E2_;
  float acc = cb[d];
  #pragma unroll
  for (int k = 0; k < 4; ++k) {
    int ls = (l + k - 3 + L_SEQ) & (L_SEQ - 1);
    acc += cw[d * 4 + k] * xzp[(size_t)ls * E2_ + d];
  }
  float s = siluf_(acc);
  size_t o = (size_t)z * L_SEQ * DI_ + idx;
  xf[o] = s;
  xbf[o] = f2bf(s);
}

// ---------------- dbc f32 -> bf16, pad 48->64 ----------------
__global__ __launch_bounds__(256) void dbcpad_kernel(const float* __restrict__ dbc,
                                                     unsigned short* __restrict__ out) {
  int z = blockIdx.z;
  int idx = blockIdx.x * 256 + threadIdx.x;           // over L*KPAD
  int l = idx >> 6, c = idx & 63;
  float v = (c < 48) ? dbc[(size_t)z * L_SEQ * DBCN + (size_t)l * DBCN + c] : 0.f;
  out[(size_t)z * L_SEQ * KPAD + idx] = f2bf(v);
}

// ---------------- chunk-parallel selective scan ----------------
__global__ __launch_bounds__(256) void scanA_kernel(const float* __restrict__ delta,
                                                    const float* __restrict__ u,
                                                    const float* __restrict__ dbc,
                                                    const float* __restrict__ Af,
                                                    const float* __restrict__ Ab, int aoff,
                                                    float* __restrict__ Pg,
                                                    float* __restrict__ Qg) {
  const int z = blockIdx.z;
  const int d0 = blockIdx.x * 16;
  const int c = blockIdx.y;
  const int tid = threadIdx.x;
  const int s = tid & 15;
  const int g = tid >> 4;
  const int d = d0 + g;
  __shared__ float sd[16 * 65], su2[16 * 65], sb2[16 * 65];
  const size_t zo = (size_t)z * L_SEQ * DI_;
  const float* dl = delta + zo;
  const float* ul = u + zo;
  const float* bc = dbc + (size_t)z * L_SEQ * DBCN;
  const float A = -__expf(((z ? Ab : Af) + aoff)[d * SSTATE + s]);
  const int l0 = c * TCH;
  #pragma unroll
  for (int i = 0; i < 4; ++i) {
    int idx = tid + i * 256;
    int di = idx & 15, li = idx >> 4;
    size_t gl = (size_t)(l0 + li);
    sd[di * 65 + li]  = dl[gl * DI_ + d0 + di];
    su2[di * 65 + li] = ul[gl * DI_ + d0 + di];
    sb2[di * 65 + li] = bc[gl * DBCN + 48 + di];
  }
  __syncthreads();
  float h = 0.f, sda = 0.f;
  #pragma unroll 4
  for (int t = 0; t < TCH; ++t) {
    float dlt = sd[g * 65 + t];
    float uu  = su2[g * 65 + t];
    float bb  = sb2[s * 65 + t];
    float a = __expf(dlt * A);
    h = a * h + dlt * uu * bb;
    sda += dlt;
  }
  size_t o = ((size_t)(z * NCHUNK + c) * DI_ + d) * SSTATE + s;
  Pg[o] = __expf(sda * A);
  Qg[o] = h;
}

__global__ __launch_bounds__(256) void scanB_kernel(const float* __restrict__ Pg,
                                                    const float* __restrict__ Qg,
                                                    float* __restrict__ hin) {
  int idx = blockIdx.x * 256 + threadIdx.x;   // over 2*DI*16
  int z = idx / (DI_ * SSTATE);
  int r = idx % (DI_ * SSTATE);
  float h = 0.f;
  #pragma unroll
  for (int c = 0; c < NCHUNK; ++c) {
    size_t o = (size_t)(z * NCHUNK + c) * DI_ * SSTATE + r;
    hin[o] = h;
    h = Pg[o] * h + Qg[o];
  }
}

__global__ __launch_bounds__(256) void scanC_kernel(const float* __restrict__ delta,
                                                    const float* __restrict__ u,
                                                    const float* __restrict__ dbc,
                                                    const float* __restrict__ xz,
                                                    const float* __restrict__ Af,
                                                    const float* __restrict__ Ab, int aoff,
                                                    const float* __restrict__ Dpf,
                                                    const float* __restrict__ Dpb, int doff,
                                                    const float* __restrict__ hin,
                                                    unsigned short* __restrict__ yb) {
  const int z = blockIdx.z;
  const int d0 = blockIdx.x * 16;
  const int c = blockIdx.y;
  const int tid = threadIdx.x;
  const int s = tid & 15;
  const int g = tid >> 4;
  const int d = d0 + g;
  __shared__ float sd[16 * 65], su2[16 * 65], sb2[16 * 65], sc2[16 * 65], sy2[16 * 65];
  const size_t zo = (size_t)z * L_SEQ * DI_;
  const float* dl = delta + zo;
  const float* ul = u + zo;
  const float* bc = dbc + (size_t)z * L_SEQ * DBCN;
  const float A = -__expf(((z ? Ab : Af) + aoff)[d * SSTATE + s]);
  const int l0 = c * TCH;
  #pragma unroll
  for (int i = 0; i < 4; ++i) {
    int idx = tid + i * 256;
    int di = idx & 15, li = idx >> 4;
    size_t gl = (size_t)(l0 + li);
    sd[di * 65 + li]  = dl[gl * DI_ + d0 + di];
    su2[di * 65 + li] = ul[gl * DI_ + d0 + di];
    sb2[di * 65 + li] = bc[gl * DBCN + 48 + di];
    sc2[di * 65 + li] = bc[gl * DBCN + 64 + di];
  }
  __syncthreads();
  float h = hin[((size_t)(z * NCHUNK + c) * DI_ + d) * SSTATE + s];
  for (int t = 0; t < TCH; t += 2) {
    float dlt0 = sd[g * 65 + t],     uu0 = su2[g * 65 + t];
    float bb0  = sb2[s * 65 + t],    cc0 = sc2[s * 65 + t];
    float dlt1 = sd[g * 65 + t + 1], uu1 = su2[g * 65 + t + 1];
    float bb1  = sb2[s * 65 + t + 1], cc1 = sc2[s * 65 + t + 1];
    float a0 = __expf(dlt0 * A); h = a0 * h + dlt0 * uu0 * bb0; float p0 = h * cc0;
    float a1 = __expf(dlt1 * A); h = a1 * h + dlt1 * uu1 * bb1; float p1 = h * cc1;
    p0 += __shfl_xor(p0, 1); p1 += __shfl_xor(p1, 1);
    p0 += __shfl_xor(p0, 2); p1 += __shfl_xor(p1, 2);
    p0 += __shfl_xor(p0, 4); p1 += __shfl_xor(p1, 4);
    p0 += __shfl_xor(p0, 8); p1 += __shfl_xor(p1, 8);
    if (s == 0) { sy2[g * 65 + t] = p0; sy2[g * 65 + t + 1] = p1; }
  }
  __syncthreads();
  const float* Dp = (z ? Dpb : Dpf) + doff;
  #pragma unroll
  for (int i = 0; i < 4; ++i) {
    int idx = tid + i * 256;
    int di = idx & 15, li = idx >> 4;
    int l = l0 + li;
    float y = sy2[di * 65 + li];
    float uu = su2[di * 65 + li];
    float zz = xz[(size_t)z * L_SEQ * E2_ + (size_t)l * E2_ + DI_ + d0 + di];
    float v = (y + Dp[d0 + di] * uu) * siluf_(zz);
    yb[zo + (size_t)l * DI_ + d0 + di] = f2bf(v);
  }
}

// ---------------- generic bf16 MFMA GEMM: C[M,N] = A[M,K] * B[N,K]^T ----------------
// global_load_lds (16B) with pre-swizzled source + XOR-swizzled ds_read (T2),
// XCD-chunked bijective block swizzle, y-fast traversal (T1).
// EPI: 0 = f32 store, 1 = softplus(v + bias[col]) f32 store, 2 = bf16 store
template <int EPI>
__global__ __launch_bounds__(256)
void gemm_bt(const unsigned short* __restrict__ Ag, long sAz,
             const unsigned short* __restrict__ Bg, long sBz,
             float* __restrict__ Cf, unsigned short* __restrict__ Cb, long sCz,
             int M, int N, int K,
             const float* __restrict__ bias, long sBiasz) {
  __shared__ __align__(16) unsigned short sA[128 * 64];
  __shared__ __align__(16) unsigned short sB[128 * 64];
  const int tid = threadIdx.x;
  const int lane = tid & 63;
  const int wv = tid >> 6;
  const int z = blockIdx.z;

  // XCD-aware chunked swizzle over y-fast linearized id (bijective, m204)
  const int nby = gridDim.y;
  const int nwg = gridDim.x * nby;
  int bid = blockIdx.x * nby + blockIdx.y;
  int q = nwg >> 3, r = nwg & 7;
  int xcd = bid & 7, slot = bid >> 3;
  int sbid = (xcd < r ? xcd * (q + 1) : r * (q + 1) + (xcd - r) * q) + slot;
  const int m0 = (sbid % nby) * 128;
  const int n0 = (sbid / nby) * 128;

  const unsigned short* A = Ag + (size_t)z * sAz;
  const unsigned short* B = Bg + (size_t)z * sBz;
  const int wm = (wv >> 1) * 64;
  const int wn = (wv & 1) * 64;
  const int lr = lane & 15;
  const int lq = lane >> 4;

  f32x4 acc[4][4] = {};

  // staging geometry: chunk p = (i*4+wv)*64 + lane (16B chunks, 8 per row)
  int prow[4], pcsw[4];
  #pragma unroll
  for (int i = 0; i < 4; ++i) {
    int p = (i * 4 + wv) * 64 + lane;
    int row = p >> 3, sl = p & 7;
    prow[i] = row;
    pcsw[i] = (sl ^ (row & 7)) * 8;   // inverse-swizzled source chunk (halfwords)
  }

  for (int k0 = 0; k0 < K; k0 += 64) {
    #pragma unroll
    for (int i = 0; i < 4; ++i) {
      int row = prow[i];
      int ra = m0 + row; if (ra > M - 1) ra = M - 1;
      int rb = n0 + row; if (rb > N - 1) rb = N - 1;
      const unsigned short* ga = A + (size_t)ra * K + k0 + pcsw[i];
      const unsigned short* gb = B + (size_t)rb * K + k0 + pcsw[i];
      __builtin_amdgcn_global_load_lds(
          (const __attribute__((address_space(1))) unsigned int*)ga,
          (__attribute__((address_space(3))) unsigned int*)(sA + (i * 4 + wv) * 512),
          16, 0, 0);
      __builtin_amdgcn_global_load_lds(
          (const __attribute__((address_space(1))) unsigned int*)gb,
          (__attribute__((address_space(3))) unsigned int*)(sB + (i * 4 + wv) * 512),
          16, 0, 0);
    }
    __syncthreads();
    #pragma unroll
    for (int kk = 0; kk < 64; kk += 32) {
      bf16x8 af[4], bfr[4];
      const int ks = (kk >> 3) + lq;
      #pragma unroll
      for (int i = 0; i < 4; ++i) {
        int rra = wm + i * 16 + lr;
        int rrb = wn + i * 16 + lr;
        af[i]  = *(const bf16x8*)(sA + rra * 64 + ((ks ^ (rra & 7)) << 3));
        bfr[i] = *(const bf16x8*)(sB + rrb * 64 + ((ks ^ (rrb & 7)) << 3));
      }
      #pragma unroll
      for (int mi = 0; mi < 4; ++mi)
        #pragma unroll
        for (int ni = 0; ni < 4; ++ni)
          acc[mi][ni] = __builtin_amdgcn_mfma_f32_16x16x32_bf16(af[mi], bfr[ni], acc[mi][ni], 0, 0, 0);
    }
    __syncthreads();
  }

  const int orow0 = m0 + wm + lq * 4;
  const int ocol0 = n0 + wn + lr;
  #pragma unroll
  for (int mi = 0; mi < 4; ++mi) {
    #pragma unroll
    for (int ni = 0; ni < 4; ++ni) {
      int col = ocol0 + ni * 16;
      if (col >= N) continue;
      #pragma unroll
      for (int j = 0; j < 4; ++j) {
        int row = orow0 + mi * 16 + j;
        if (row >= M) continue;
        float v = acc[mi][ni][j];
        if constexpr (EPI == 1) v = softplusf_(v + bias[(size_t)z * sBiasz + col]);
        if constexpr (EPI == 2) {
          Cb[(size_t)z * sCz + (size_t)row * N + col] = f2bf(v);
        } else {
          Cf[(size_t)z * sCz + (size_t)row * N + col] = v;
        }
      }
    }
  }
}

// ==================== host launcher ====================
extern "C" void kernel_launch(void* const* d_in, const int* in_sizes, int n_in,
                              void* d_out, int out_size, void* d_ws, size_t ws_size,
                              hipStream_t stream) {
  const int* ids = (const int*)d_in[0];
  const float* embedding = (const float*)d_in[1];
  const float* lm_head = (const float*)d_in[2];
  const float* F[11]; const float* Bp[11];
  for (int i = 0; i < 11; ++i) { F[i] = (const float*)d_in[3 + i]; Bp[i] = (const float*)d_in[14 + i]; }

  char* ws = (char*)d_ws;
  size_t off = 0;
  auto AL = [&](size_t bytes) { size_t o = off; off += (bytes + 255) & ~(size_t)255; return o; };
  size_t o_win  = AL((size_t)2 * NLAYER * E2_ * DMODEL * 2);
  size_t o_wxp  = AL((size_t)2 * NLAYER * DBCN * DI_ * 2);
  size_t o_wdtw = AL((size_t)2 * NLAYER * DI_ * KPAD * 2);
  size_t o_wout = AL((size_t)2 * NLAYER * DMODEL * DI_ * 2);
  size_t o_wlm  = AL((size_t)DMODEL * DI_ * 2);
  size_t o_wemb = AL((size_t)VOCAB * DMODEL * 2);
  size_t o_dtb  = AL((size_t)2 * NLAYER * DI_ * 4);
  size_t o_res  = AL((size_t)2 * L_SEQ * DMODEL * 4);
  size_t o_hid  = AL((size_t)2 * L_SEQ * DMODEL * 4);
  size_t o_hn   = AL((size_t)2 * L_SEQ * DMODEL * 2);
  size_t o_xz   = AL((size_t)2 * L_SEQ * E2_ * 4);
  size_t o_xc   = AL((size_t)2 * L_SEQ * DI_ * 4);
  size_t o_xcb  = AL((size_t)2 * L_SEQ * DI_ * 2);
  size_t o_dbc  = AL((size_t)2 * L_SEQ * DBCN * 4);
  size_t o_dbcb = AL((size_t)2 * L_SEQ * KPAD * 2);
  size_t o_dlt  = AL((size_t)2 * L_SEQ * DI_ * 4);
  size_t o_P    = AL((size_t)2 * NCHUNK * DI_ * SSTATE * 4);
  size_t o_Q    = AL((size_t)2 * NCHUNK * DI_ * SSTATE * 4);
  size_t o_hin  = AL((size_t)2 * NCHUNK * DI_ * SSTATE * 4);
  size_t o_yb   = AL((size_t)2 * L_SEQ * DI_ * 2);
  size_t o_hcat = AL((size_t)L_SEQ * DI_ * 2);
  size_t o_proj = AL((size_t)L_SEQ * DMODEL * 2);
  if (ws_size < off) return;

  unsigned short* w_in  = (unsigned short*)(ws + o_win);
  unsigned short* w_xp  = (unsigned short*)(ws + o_wxp);
  unsigned short* w_dtw = (unsigned short*)(ws + o_wdtw);
  unsigned short* w_out = (unsigned short*)(ws + o_wout);
  unsigned short* w_lm  = (unsigned short*)(ws + o_wlm);
  unsigned short* w_emb = (unsigned short*)(ws + o_wemb);
  float* dtb = (float*)(ws + o_dtb);
  float* res = (float*)(ws + o_res);
  float* hid = (float*)(ws + o_hid);
  unsigned short* hn = (unsigned short*)(ws + o_hn);
  float* xz = (float*)(ws + o_xz);
  float* xc = (float*)(ws + o_xc);
  unsigned short* xcb = (unsigned short*)(ws + o_xcb);
  float* dbc = (float*)(ws + o_dbc);
  unsigned short* dbcb = (unsigned short*)(ws + o_dbcb);
  float* dlt = (float*)(ws + o_dlt);
  float* Pg  = (float*)(ws + o_P);
  float* Qg  = (float*)(ws + o_Q);
  float* hing = (float*)(ws + o_hin);
  unsigned short* yb = (unsigned short*)(ws + o_yb);
  unsigned short* hcat = (unsigned short*)(ws + o_hcat);
  unsigned short* projb = (unsigned short*)(ws + o_proj);
  float* logits = (float*)d_out;

  // ---- weight conversions ----
  {
    long n = (long)NLAYER * E2_ * DMODEL;
    cvt2_kernel<<<dim3((n / 4 + 255) / 256, 1, 2), 256, 0, stream>>>(F[0], Bp[0], w_in, n);
    n = (long)NLAYER * DBCN * DI_;
    cvt2_kernel<<<dim3((n / 4 + 255) / 256, 1, 2), 256, 0, stream>>>(F[3], Bp[3], w_xp, n);
    cvtdtw_kernel<<<dim3(((long)NLAYER * DI_ * KPAD + 255) / 256, 1, 2), 256, 0, stream>>>(F[4], Bp[4], w_dtw);
    n = (long)NLAYER * DMODEL * DI_;
    cvt2_kernel<<<dim3((n / 4 + 255) / 256, 1, 2), 256, 0, stream>>>(F[8], Bp[8], w_out, n);
    n = (long)DMODEL * DI_;
    cvt1_kernel<<<dim3((n / 4 + 255) / 256, 1, 1), 256, 0, stream>>>(lm_head, w_lm, n);
    n = (long)VOCAB * DMODEL;
    cvt1_kernel<<<dim3((n / 4 + 255) / 256, 1, 1), 256, 0, stream>>>(embedding, w_emb, n);
    hipMemcpyAsync(dtb, F[5], (size_t)NLAYER * DI_ * 4, hipMemcpyDeviceToDevice, stream);
    hipMemcpyAsync(dtb + NLAYER * DI_, Bp[5], (size_t)NLAYER * DI_ * 4, hipMemcpyDeviceToDevice, stream);
  }

  gather_kernel<<<dim3(L_SEQ * DMODEL / 256, 1, 2), 256, 0, stream>>>(ids, embedding, res);

  for (int layer = 0; layer < NLAYER; ++layer) {
    addnorm_kernel<<<dim3(L_SEQ, 1, 2), 256, 0, stream>>>(
        res, layer ? hid : nullptr, F[9], Bp[9], layer * DMODEL, hn);
    // xz = hn @ in_proj^T  (M=2048, N=3072, K=768)
    gemm_bt<0><<<dim3(E2_ / 128, L_SEQ / 128, 2), 256, 0, stream>>>(
        hn, (long)L_SEQ * DMODEL,
        w_in + (size_t)layer * E2_ * DMODEL, (long)NLAYER * E2_ * DMODEL,
        xz, nullptr, (long)L_SEQ * E2_, L_SEQ, E2_, DMODEL, nullptr, 0);
    conv_kernel<<<dim3(L_SEQ * DI_ / 256, 1, 2), 256, 0, stream>>>(
        xz, F[1], Bp[1], F[2], Bp[2], layer, xc, xcb);
    // dbc = x @ x_proj^T (M=2048, N=80, K=1536)
    gemm_bt<0><<<dim3(1, L_SEQ / 128, 2), 256, 0, stream>>>(
        xcb, (long)L_SEQ * DI_,
        w_xp + (size_t)layer * DBCN * DI_, (long)NLAYER * DBCN * DI_,
        dbc, nullptr, (long)L_SEQ * DBCN, L_SEQ, DBCN, DI_, nullptr, 0);
    dbcpad_kernel<<<dim3(L_SEQ * KPAD / 256, 1, 2), 256, 0, stream>>>(dbc, dbcb);
    // delta = softplus(dbc[:, :48] @ dt_w^T + dt_b) (M=2048, N=1536, K=64)
    gemm_bt<1><<<dim3(DI_ / 128, L_SEQ / 128, 2), 256, 0, stream>>>(
        dbcb, (long)L_SEQ * KPAD,
        w_dtw + (size_t)layer * DI_ * KPAD, (long)NLAYER * DI_ * KPAD,
        dlt, nullptr, (long)L_SEQ * DI_, L_SEQ, DI_, KPAD,
        dtb + layer * DI_, (long)NLAYER * DI_);
    // chunk-parallel scan
    scanA_kernel<<<dim3(DI_ / 16, NCHUNK, 2), 256, 0, stream>>>(
        dlt, xc, dbc, F[6], Bp[6], layer * DI_ * SSTATE, Pg, Qg);
    scanB_kernel<<<dim3(2 * DI_ * SSTATE / 256, 1, 1), 256, 0, stream>>>(Pg, Qg, hing);
    scanC_kernel<<<dim3(DI_ / 16, NCHUNK, 2), 256, 0, stream>>>(
        dlt, xc, dbc, xz, F[6], Bp[6], layer * DI_ * SSTATE,
        F[7], Bp[7], layer * DI_, hing, yb);
    // hid = y @ out_proj^T (M=2048, N=768, K=1536)
    gemm_bt<0><<<dim3(DMODEL / 128, L_SEQ / 128, 2), 256, 0, stream>>>(
        yb, (long)L_SEQ * DI_,
        w_out + (size_t)layer * DMODEL * DI_, (long)NLAYER * DMODEL * DI_,
        hid, nullptr, (long)L_SEQ * DMODEL, L_SEQ, DMODEL, DI_, nullptr, 0);
  }

  finalcat_kernel<<<dim3(L_SEQ, 1, 2), 256, 0, stream>>>(res, hid, F[10], Bp[10], hcat);
  // proj = hcat @ lm_head^T (M=2048, N=768, K=1536) -> bf16
  gemm_bt<2><<<dim3(DMODEL / 128, L_SEQ / 128, 1), 256, 0, stream>>>(
      hcat, 0, w_lm, 0, nullptr, projb, 0, L_SEQ, DMODEL, DI_, nullptr, 0);
  // logits = proj @ embedding^T (M=2048, N=32000, K=768) -> f32 d_out
  gemm_bt<0><<<dim3(VOCAB / 128, L_SEQ / 128, 1), 256, 0, stream>>>(
      projb, 0, w_emb, 0, logits, nullptr, 0, L_SEQ, VOCAB, DMODEL, nullptr, 0);
}